// Round 2
// baseline (2281.073 us; speedup 1.0000x reference)
//
#include <hip/hip_runtime.h>
#include <math.h>

// Problem constants (fixed by reference): N=50000, E=400000, U=32, R=32
// ALL float tensors are float32 (verified round 1: threshold had no bf16 floor);
// edge_index is int32. d_out is float*.
//
// Algebraic simplification: message passing gathers at dst and scatters to dst
// (edge_index[0] unused), so msg[n] = I[n]*sI[n,u] + A[n]*sA[n,u] + S[n]*sS[n,u]
// where sI/sA/sS[n,u] are scatter-sums of the 96 edge-MLP outputs per edge.

__device__ __forceinline__ float fast_silu(float x){
    // x * sigmoid(x) = x / (1 + e^-x); overflow-safe: expf(+inf-ish) -> inf -> x/inf = 0
    return x / (1.0f + expf(-x));
}

// ---------------- prep: transpose Wt [6][32m][32k] -> wtT [6][32k][32m] -------
__global__ __launch_bounds__(256) void prep_kernel(
    const float* __restrict__ Wt, float* __restrict__ wtT)
{
    int i = blockIdx.x * 256 + threadIdx.x;
    if (i < 6144) {
        int l = i >> 10, rem = i & 1023, k = rem >> 5, m = rem & 31;
        wtT[i] = Wt[(l << 10) + (m << 5) + k];
    }
}

// ---------------- edge: cutoff * 3-layer silu MLP, scatter-add 96 scalars -----
__global__ __launch_bounds__(256) void edge_mlp_kernel(
    const float* __restrict__ edge_attr,
    const float* __restrict__ edge_weight,
    const int* __restrict__ edge_index,
    const float* __restrict__ w1, const float* __restrict__ b1,
    const float* __restrict__ w2, const float* __restrict__ b2,
    const float* __restrict__ w3, const float* __restrict__ b3,
    float* __restrict__ acc, int nE)
{
    int e = blockIdx.x * 256 + threadIdx.x;
    if (e >= nE) return;

    // load edge_attr row: 32 f32 = 128B = 8x float4, coalesced
    const float4* rq = reinterpret_cast<const float4*>(edge_attr) + (size_t)e * 8;
    float ea[32];
    #pragma unroll
    for (int i = 0; i < 8; ++i) {
        float4 q = rq[i];
        ea[4*i] = q.x; ea[4*i+1] = q.y; ea[4*i+2] = q.z; ea[4*i+3] = q.w;
    }

    // layer 1: 32 -> 32 (weight indices wave-uniform -> s_load + v_fmac w/ sgpr)
    float h1[32];
    for (int m = 0; m < 32; ++m) {
        float a = b1[m];
        #pragma unroll
        for (int r = 0; r < 32; ++r) a += ea[r] * w1[m*32 + r];
        h1[m] = fast_silu(a);
    }
    // layer 2: 32 -> 64
    float h2[64];
    for (int m = 0; m < 64; ++m) {
        float a = b2[m];
        #pragma unroll
        for (int k = 0; k < 32; ++k) a += h1[k] * w2[m*32 + k];
        h2[m] = fast_silu(a);
    }
    // cosine cutoff
    float ew = edge_weight[e];
    float Cc = (ew < 5.0f) ? 0.5f * (cosf(ew * (3.14159265358979323846f/5.0f)) + 1.0f) : 0.0f;
    int dst = edge_index[nE + e];  // edge_index[1][e]; row 0 is unused by the reference
    float* ap = acc + (size_t)dst * 96;
    // layer 3: 64 -> 96, silu, *Cc, scatter (m = unit*3 + comp matches acc layout)
    for (int m = 0; m < 96; ++m) {
        float a = b3[m];
        #pragma unroll
        for (int k = 0; k < 64; ++k) a += h2[k] * w3[m*64 + k];
        a = fast_silu(a) * Cc;
        atomicAdd(ap + m, a);
    }
}

// ---------------- node: normalize, decompose, lin, msg, O(3) product, lin, out -
// block = 256 threads = 8 nodes x 32 units. Thread handles unit u of node ln.
__device__ __forceinline__ void comp_linear(
    const float* __restrict__ w012,   // [3][32k][32m] (k-major)
    const float* __restrict__ cb,     // [10][32k] components of this node
    int u, float& Il, float* a, float* s)
{
    Il = 0.f; a[0]=a[1]=a[2]=0.f;
    s[0]=s[1]=s[2]=s[3]=s[4]=s[5]=0.f;
    #pragma unroll
    for (int k = 0; k < 32; ++k) {
        float w0 = w012[          k*32 + u];
        float w1 = w012[1024 + k*32 + u];
        float w2 = w012[2048 + k*32 + u];
        Il   += cb[       k] * w0;
        a[0] += cb[ 32 + k] * w1;
        a[1] += cb[ 64 + k] * w1;
        a[2] += cb[ 96 + k] * w1;
        s[0] += cb[128 + k] * w2;
        s[1] += cb[160 + k] * w2;
        s[2] += cb[192 + k] * w2;
        s[3] += cb[224 + k] * w2;
        s[4] += cb[256 + k] * w2;
        s[5] += cb[288 + k] * w2;
    }
}

__device__ __forceinline__ void compose(float Il, const float* a, const float* s, float (&T)[3][3])
{
    // s: s00,s01,s02,s11,s12,s22 ; a: a01,a02,a12
    T[0][0] =  Il  + s[0]; T[0][1] =  a[0] + s[1]; T[0][2] =  a[1] + s[2];
    T[1][0] = -a[0] + s[1]; T[1][1] =  Il  + s[3]; T[1][2] =  a[2] + s[4];
    T[2][0] = -a[1] + s[2]; T[2][1] = -a[2] + s[4]; T[2][2] =  Il  + s[5];
}

__global__ __launch_bounds__(256) void node_kernel(
    const float* __restrict__ X,
    const float* __restrict__ wtT,    // [6][32k][32m]
    const float* __restrict__ acc,    // [N][32u][3c]
    float* __restrict__ out, int nN)
{
    __shared__ float sWt[6 * 1024];
    __shared__ float sC[8][10][32];

    int tid = threadIdx.x;
    for (int i = tid; i < 6144; i += 256) sWt[i] = wtT[i];

    int ln = tid >> 5, u = tid & 31;
    int n  = blockIdx.x * 8 + ln;
    if (n >= nN) n = nN - 1;               // redundant work, no divergence (N%8==0 anyway)
    float* cb = &sC[ln][0][0];

    // load X[n,:,:,u] (coalesced: consecutive u -> consecutive floats), normalize
    const float* xp = X + (size_t)n * 288 + u;
    float x[3][3];
    float nrm = 1.0f;
    #pragma unroll
    for (int i = 0; i < 3; ++i)
        #pragma unroll
        for (int j = 0; j < 3; ++j) {
            float v = xp[(i*3 + j) * 32];
            x[i][j] = v; nrm += v * v;
        }
    float inv = 1.0f / nrm;
    #pragma unroll
    for (int i = 0; i < 3; ++i)
        #pragma unroll
        for (int j = 0; j < 3; ++j) x[i][j] *= inv;   // x = Xn

    // decompose Xn -> 10 components in LDS
    float tI = (x[0][0] + x[1][1] + x[2][2]) * (1.0f/3.0f);
    cb[0*32 + u] = tI;
    cb[1*32 + u] = 0.5f * (x[0][1] - x[1][0]);
    cb[2*32 + u] = 0.5f * (x[0][2] - x[2][0]);
    cb[3*32 + u] = 0.5f * (x[1][2] - x[2][1]);
    cb[4*32 + u] = x[0][0] - tI;
    cb[5*32 + u] = 0.5f * (x[0][1] + x[1][0]);
    cb[6*32 + u] = 0.5f * (x[0][2] + x[2][0]);
    cb[7*32 + u] = x[1][1] - tI;
    cb[8*32 + u] = 0.5f * (x[1][2] + x[2][1]);
    cb[9*32 + u] = x[2][2] - tI;
    __syncthreads();

    // linear round 1 (Wt0/1/2)
    float Il, a[3], s[6];
    comp_linear(sWt, cb, u, Il, a, s);

    // edge-sum scalars for this (n,u)
    const float* ap = acc + (size_t)n * 96 + u * 3;
    float sIv = ap[0], sAv = ap[1], sSv = ap[2];

    float Ym[3][3], Gm[3][3];
    compose(Il, a, s, Ym);
    float am[3] = {a[0]*sAv, a[1]*sAv, a[2]*sAv};
    float sm[6] = {s[0]*sSv, s[1]*sSv, s[2]*sSv, s[3]*sSv, s[4]*sSv, s[5]*sSv};
    compose(Il * sIv, am, sm, Gm);

    // M = Y*G + G*Y ; normp1
    float M[3][3]; float np1 = 1.0f;
    #pragma unroll
    for (int i = 0; i < 3; ++i)
        #pragma unroll
        for (int l = 0; l < 3; ++l) {
            float v = 0.f;
            #pragma unroll
            for (int j = 0; j < 3; ++j) v += Ym[i][j]*Gm[j][l] + Gm[i][j]*Ym[j][l];
            M[i][l] = v; np1 += v * v;
        }
    float rinv = 1.0f / np1;
    float tI2 = (M[0][0] + M[1][1] + M[2][2]) * (1.0f/3.0f);

    __syncthreads();   // round-1 comps fully consumed
    cb[0*32 + u] = tI2 * rinv;
    cb[1*32 + u] = 0.5f * (M[0][1] - M[1][0]) * rinv;
    cb[2*32 + u] = 0.5f * (M[0][2] - M[2][0]) * rinv;
    cb[3*32 + u] = 0.5f * (M[1][2] - M[2][1]) * rinv;
    cb[4*32 + u] = (M[0][0] - tI2) * rinv;
    cb[5*32 + u] = 0.5f * (M[0][1] + M[1][0]) * rinv;
    cb[6*32 + u] = 0.5f * (M[0][2] + M[2][0]) * rinv;
    cb[7*32 + u] = (M[1][1] - tI2) * rinv;
    cb[8*32 + u] = 0.5f * (M[1][2] + M[2][1]) * rinv;
    cb[9*32 + u] = (M[2][2] - tI2) * rinv;
    __syncthreads();

    // linear round 2 (Wt3/4/5) -> dX
    comp_linear(sWt + 3*1024, cb, u, Il, a, s);
    float D[3][3];
    compose(Il, a, s, D);

    // out = Xn + dX + dX@dX
    float* op = out + (size_t)n * 288 + u;
    #pragma unroll
    for (int i = 0; i < 3; ++i)
        #pragma unroll
        for (int l = 0; l < 3; ++l) {
            float v = x[i][l] + D[i][l];
            #pragma unroll
            for (int j = 0; j < 3; ++j) v += D[i][j] * D[j][l];
            op[(i*3 + l) * 32] = v;
        }
}

extern "C" void kernel_launch(void* const* d_in, const int* in_sizes, int n_in,
                              void* d_out, int out_size, void* d_ws, size_t ws_size,
                              hipStream_t stream) {
    const float* X   = (const float*)d_in[0];
    const int*   ei  = (const int*)d_in[1];
    const float* ew  = (const float*)d_in[2];
    const float* ea  = (const float*)d_in[3];
    const float* W1  = (const float*)d_in[4];
    const float* b1  = (const float*)d_in[5];
    const float* W2  = (const float*)d_in[6];
    const float* b2  = (const float*)d_in[7];
    const float* W3  = (const float*)d_in[8];
    const float* b3  = (const float*)d_in[9];
    const float* Wt  = (const float*)d_in[10];

    int nE = in_sizes[2];          // 400000
    int nN = in_sizes[0] / 288;    // 50000

    float* ws   = (float*)d_ws;
    float* accp = ws;                          // N*96 floats (19.2 MB)
    float* wtT  = ws + (size_t)nN * 96;        // 6144 floats

    hipMemsetAsync(accp, 0, (size_t)nN * 96 * sizeof(float), stream);
    prep_kernel<<<24, 256, 0, stream>>>(Wt, wtT);
    edge_mlp_kernel<<<(nE + 255) / 256, 256, 0, stream>>>(
        ea, ew, ei, W1, b1, W2, b2, W3, b3, accp, nE);
    node_kernel<<<(nN + 7) / 8, 256, 0, stream>>>(X, wtT, accp, (float*)d_out, nN);
}

// Round 3
// 1172.185 us; speedup vs baseline: 1.9460x; 1.9460x over previous
//
#include <hip/hip_runtime.h>
#include <math.h>

// N=50000, E=400000, U=32, R=32. All float tensors fp32; edge_index int32.
//
// R2 post-mortem: 38.4M scattered fp32 atomics (96/edge) cost ~34B RMW each ->
// WRITE_SIZE 1.3GB, atomic-throughput-bound at ~640 GB/s (2080us, VALUBusy 7%).
// R3: CSR over dst (each edge hits exactly one node), MLP stores 96 floats/edge
// contiguously (coalesced, write-back cached), node kernel gathers+sums its
// edges' outputs directly (384B contiguous per edge across the 32 unit-lanes).
// Atomics drop 38.4M -> 0.8M (int CSR build only).

__device__ __forceinline__ float fast_silu(float x){
    return x / (1.0f + expf(-x));   // overflow-safe silu
}

// ---------------- prep: transpose Wt [6][32m][32k] -> wtT [6][32k][32m] -------
__global__ __launch_bounds__(256) void prep_kernel(
    const float* __restrict__ Wt, float* __restrict__ wtT)
{
    int i = blockIdx.x * 256 + threadIdx.x;
    if (i < 6144) {
        int l = i >> 10, rem = i & 1023, k = rem >> 5, m = rem & 31;
        wtT[i] = Wt[(l << 10) + (m << 5) + k];
    }
}

// ---------------- CSR build ---------------------------------------------------
__global__ __launch_bounds__(256) void hist_kernel(
    const int* __restrict__ edge_index, int* __restrict__ cnt, int nE)
{
    int e = blockIdx.x * 256 + threadIdx.x;
    if (e < nE) atomicAdd(&cnt[edge_index[nE + e]], 1);
}

// single-block exclusive scan over nN counters -> rowptr[0..nN]
__global__ __launch_bounds__(1024) void scan_kernel(
    const int* __restrict__ cnt, int* __restrict__ rowptr, int nN)
{
    __shared__ int wsum[16];
    __shared__ int wpre[16];
    __shared__ int running;
    int tid = threadIdx.x, lane = tid & 63, wid = tid >> 6;
    if (tid == 0) running = 0;
    __syncthreads();
    for (int base = 0; base < nN; base += 1024) {
        int i = base + tid;
        int orig = (i < nN) ? cnt[i] : 0;
        int v = orig;
        #pragma unroll
        for (int d = 1; d < 64; d <<= 1) { int o = __shfl_up(v, d); if (lane >= d) v += o; }
        if (lane == 63) wsum[wid] = v;
        __syncthreads();
        if (wid == 0) {
            int s = (lane < 16) ? wsum[lane] : 0;
            #pragma unroll
            for (int d = 1; d < 16; d <<= 1) { int o = __shfl_up(s, d); if (lane >= d) s += o; }
            if (lane < 16) wpre[lane] = s;
        }
        __syncthreads();
        int badd = running + (wid ? wpre[wid - 1] : 0);
        if (i < nN) rowptr[i] = badd + v - orig;   // exclusive
        __syncthreads();
        if (tid == 0) running += wpre[15];
        __syncthreads();
    }
    if (threadIdx.x == 0) rowptr[nN] = running;
}

__global__ __launch_bounds__(256) void bump_kernel(
    const int* __restrict__ edge_index, const int* __restrict__ rowptr,
    int* __restrict__ cursor, int* __restrict__ eids, int nE)
{
    int e = blockIdx.x * 256 + threadIdx.x;
    if (e >= nE) return;
    int dst = edge_index[nE + e];
    int slot = atomicAdd(&cursor[dst], 1);
    eids[rowptr[dst] + slot] = e;
}

// ---------------- edge: cutoff * 3-layer silu MLP, store 96 floats ------------
__global__ __launch_bounds__(256) void edge_mlp_store_kernel(
    const float* __restrict__ edge_attr,
    const float* __restrict__ edge_weight,
    const float* __restrict__ w1, const float* __restrict__ b1,
    const float* __restrict__ w2, const float* __restrict__ b2,
    const float* __restrict__ w3, const float* __restrict__ b3,
    float* __restrict__ buf, int nE)
{
    int e = blockIdx.x * 256 + threadIdx.x;
    if (e >= nE) return;

    const float4* rq = reinterpret_cast<const float4*>(edge_attr) + (size_t)e * 8;
    float ea[32];
    #pragma unroll
    for (int i = 0; i < 8; ++i) {
        float4 q = rq[i];
        ea[4*i] = q.x; ea[4*i+1] = q.y; ea[4*i+2] = q.z; ea[4*i+3] = q.w;
    }

    float h1[32];
    for (int m = 0; m < 32; ++m) {
        float a = b1[m];
        #pragma unroll
        for (int r = 0; r < 32; ++r) a += ea[r] * w1[m*32 + r];
        h1[m] = fast_silu(a);
    }
    float h2[64];
    for (int m = 0; m < 64; ++m) {
        float a = b2[m];
        #pragma unroll
        for (int k = 0; k < 32; ++k) a += h1[k] * w2[m*32 + k];
        h2[m] = fast_silu(a);
    }
    float ew = edge_weight[e];
    float Cc = (ew < 5.0f) ? 0.5f * (cosf(ew * (3.14159265358979323846f/5.0f)) + 1.0f) : 0.0f;

    float4* op = reinterpret_cast<float4*>(buf + (size_t)e * 96);
    for (int m4 = 0; m4 < 24; ++m4) {
        float o[4];
        #pragma unroll
        for (int j = 0; j < 4; ++j) {
            int m = m4 * 4 + j;
            float a = b3[m];
            #pragma unroll
            for (int k = 0; k < 64; ++k) a += h2[k] * w3[m*64 + k];
            o[j] = fast_silu(a) * Cc;
        }
        op[m4] = make_float4(o[0], o[1], o[2], o[3]);
    }
}

// ---------------- fallback edge kernel (atomic scatter) -----------------------
__global__ __launch_bounds__(256) void edge_mlp_atomic_kernel(
    const float* __restrict__ edge_attr,
    const float* __restrict__ edge_weight,
    const int* __restrict__ edge_index,
    const float* __restrict__ w1, const float* __restrict__ b1,
    const float* __restrict__ w2, const float* __restrict__ b2,
    const float* __restrict__ w3, const float* __restrict__ b3,
    float* __restrict__ acc, int nE)
{
    int e = blockIdx.x * 256 + threadIdx.x;
    if (e >= nE) return;
    const float4* rq = reinterpret_cast<const float4*>(edge_attr) + (size_t)e * 8;
    float ea[32];
    #pragma unroll
    for (int i = 0; i < 8; ++i) {
        float4 q = rq[i];
        ea[4*i] = q.x; ea[4*i+1] = q.y; ea[4*i+2] = q.z; ea[4*i+3] = q.w;
    }
    float h1[32];
    for (int m = 0; m < 32; ++m) {
        float a = b1[m];
        #pragma unroll
        for (int r = 0; r < 32; ++r) a += ea[r] * w1[m*32 + r];
        h1[m] = fast_silu(a);
    }
    float h2[64];
    for (int m = 0; m < 64; ++m) {
        float a = b2[m];
        #pragma unroll
        for (int k = 0; k < 32; ++k) a += h1[k] * w2[m*32 + k];
        h2[m] = fast_silu(a);
    }
    float ew = edge_weight[e];
    float Cc = (ew < 5.0f) ? 0.5f * (cosf(ew * (3.14159265358979323846f/5.0f)) + 1.0f) : 0.0f;
    int dst = edge_index[nE + e];
    float* ap = acc + (size_t)dst * 96;
    for (int m = 0; m < 96; ++m) {
        float a = b3[m];
        #pragma unroll
        for (int k = 0; k < 64; ++k) a += h2[k] * w3[m*64 + k];
        atomicAdd(ap + m, fast_silu(a) * Cc);
    }
}

// ---------------- node kernel -------------------------------------------------
__device__ __forceinline__ void comp_linear(
    const float* __restrict__ w012, const float* __restrict__ cb,
    int u, float& Il, float* a, float* s)
{
    Il = 0.f; a[0]=a[1]=a[2]=0.f;
    s[0]=s[1]=s[2]=s[3]=s[4]=s[5]=0.f;
    #pragma unroll
    for (int k = 0; k < 32; ++k) {
        float w0 = w012[          k*32 + u];
        float w1 = w012[1024 + k*32 + u];
        float w2 = w012[2048 + k*32 + u];
        Il   += cb[       k] * w0;
        a[0] += cb[ 32 + k] * w1;
        a[1] += cb[ 64 + k] * w1;
        a[2] += cb[ 96 + k] * w1;
        s[0] += cb[128 + k] * w2;
        s[1] += cb[160 + k] * w2;
        s[2] += cb[192 + k] * w2;
        s[3] += cb[224 + k] * w2;
        s[4] += cb[256 + k] * w2;
        s[5] += cb[288 + k] * w2;
    }
}

__device__ __forceinline__ void compose(float Il, const float* a, const float* s, float (&T)[3][3])
{
    T[0][0] =  Il  + s[0]; T[0][1] =  a[0] + s[1]; T[0][2] =  a[1] + s[2];
    T[1][0] = -a[0] + s[1]; T[1][1] =  Il  + s[3]; T[1][2] =  a[2] + s[4];
    T[2][0] = -a[1] + s[2]; T[2][1] = -a[2] + s[4]; T[2][2] =  Il  + s[5];
}

__global__ __launch_bounds__(256) void node_kernel(
    const float* __restrict__ X,
    const float* __restrict__ wtT,      // [6][32k][32m]
    const float* __restrict__ acc,      // fallback path: [N][32u][3c] (or null)
    const int* __restrict__ rowptr,     // CSR path
    const int* __restrict__ eids,
    const float* __restrict__ buf,      // [E][96]
    float* __restrict__ out, int nN, int use_csr)
{
    __shared__ float sWt[6 * 1024];
    __shared__ float sC[8][10][32];

    int tid = threadIdx.x;
    for (int i = tid; i < 6144; i += 256) sWt[i] = wtT[i];

    int ln = tid >> 5, u = tid & 31;
    int n  = blockIdx.x * 8 + ln;
    if (n >= nN) n = nN - 1;
    float* cb = &sC[ln][0][0];

    // edge-message sums for this (n,u) — start loads early
    float sIv = 0.f, sAv = 0.f, sSv = 0.f;
    if (use_csr) {
        int r0 = rowptr[n], r1 = rowptr[n + 1];
        for (int i = r0; i < r1; ++i) {
            int eid = eids[i];
            const float* bp = buf + (size_t)eid * 96 + 3 * u;
            sIv += bp[0]; sAv += bp[1]; sSv += bp[2];
        }
    } else {
        const float* ap = acc + (size_t)n * 96 + u * 3;
        sIv = ap[0]; sAv = ap[1]; sSv = ap[2];
    }

    const float* xp = X + (size_t)n * 288 + u;
    float x[3][3];
    float nrm = 1.0f;
    #pragma unroll
    for (int i = 0; i < 3; ++i)
        #pragma unroll
        for (int j = 0; j < 3; ++j) {
            float v = xp[(i*3 + j) * 32];
            x[i][j] = v; nrm += v * v;
        }
    float inv = 1.0f / nrm;
    #pragma unroll
    for (int i = 0; i < 3; ++i)
        #pragma unroll
        for (int j = 0; j < 3; ++j) x[i][j] *= inv;   // Xn

    float tI = (x[0][0] + x[1][1] + x[2][2]) * (1.0f/3.0f);
    cb[0*32 + u] = tI;
    cb[1*32 + u] = 0.5f * (x[0][1] - x[1][0]);
    cb[2*32 + u] = 0.5f * (x[0][2] - x[2][0]);
    cb[3*32 + u] = 0.5f * (x[1][2] - x[2][1]);
    cb[4*32 + u] = x[0][0] - tI;
    cb[5*32 + u] = 0.5f * (x[0][1] + x[1][0]);
    cb[6*32 + u] = 0.5f * (x[0][2] + x[2][0]);
    cb[7*32 + u] = x[1][1] - tI;
    cb[8*32 + u] = 0.5f * (x[1][2] + x[2][1]);
    cb[9*32 + u] = x[2][2] - tI;
    __syncthreads();

    float Il, a[3], s[6];
    comp_linear(sWt, cb, u, Il, a, s);

    float Ym[3][3], Gm[3][3];
    compose(Il, a, s, Ym);
    float am[3] = {a[0]*sAv, a[1]*sAv, a[2]*sAv};
    float sm[6] = {s[0]*sSv, s[1]*sSv, s[2]*sSv, s[3]*sSv, s[4]*sSv, s[5]*sSv};
    compose(Il * sIv, am, sm, Gm);

    float M[3][3]; float np1 = 1.0f;
    #pragma unroll
    for (int i = 0; i < 3; ++i)
        #pragma unroll
        for (int l = 0; l < 3; ++l) {
            float v = 0.f;
            #pragma unroll
            for (int j = 0; j < 3; ++j) v += Ym[i][j]*Gm[j][l] + Gm[i][j]*Ym[j][l];
            M[i][l] = v; np1 += v * v;
        }
    float rinv = 1.0f / np1;
    float tI2 = (M[0][0] + M[1][1] + M[2][2]) * (1.0f/3.0f);

    __syncthreads();
    cb[0*32 + u] = tI2 * rinv;
    cb[1*32 + u] = 0.5f * (M[0][1] - M[1][0]) * rinv;
    cb[2*32 + u] = 0.5f * (M[0][2] - M[2][0]) * rinv;
    cb[3*32 + u] = 0.5f * (M[1][2] - M[2][1]) * rinv;
    cb[4*32 + u] = (M[0][0] - tI2) * rinv;
    cb[5*32 + u] = 0.5f * (M[0][1] + M[1][0]) * rinv;
    cb[6*32 + u] = 0.5f * (M[0][2] + M[2][0]) * rinv;
    cb[7*32 + u] = (M[1][1] - tI2) * rinv;
    cb[8*32 + u] = 0.5f * (M[1][2] + M[2][1]) * rinv;
    cb[9*32 + u] = (M[2][2] - tI2) * rinv;
    __syncthreads();

    comp_linear(sWt + 3*1024, cb, u, Il, a, s);
    float D[3][3];
    compose(Il, a, s, D);

    float* op = out + (size_t)n * 288 + u;
    #pragma unroll
    for (int i = 0; i < 3; ++i)
        #pragma unroll
        for (int l = 0; l < 3; ++l) {
            float v = x[i][l] + D[i][l];
            #pragma unroll
            for (int j = 0; j < 3; ++j) v += D[i][j] * D[j][l];
            op[(i*3 + l) * 32] = v;
        }
}

extern "C" void kernel_launch(void* const* d_in, const int* in_sizes, int n_in,
                              void* d_out, int out_size, void* d_ws, size_t ws_size,
                              hipStream_t stream) {
    const float* X   = (const float*)d_in[0];
    const int*   ei  = (const int*)d_in[1];
    const float* ew  = (const float*)d_in[2];
    const float* ea  = (const float*)d_in[3];
    const float* W1  = (const float*)d_in[4];
    const float* b1  = (const float*)d_in[5];
    const float* W2  = (const float*)d_in[6];
    const float* b2  = (const float*)d_in[7];
    const float* W3  = (const float*)d_in[8];
    const float* b3  = (const float*)d_in[9];
    const float* Wt  = (const float*)d_in[10];

    int nE = in_sizes[2];          // 400000
    int nN = in_sizes[0] / 288;    // 50000

    float* ws  = (float*)d_ws;
    float* wtT = ws;                           // 6144 floats (+pad to 8192)

    // CSR layout: buf [nE*96] floats, then int arrays
    float* buf = ws + 8192;
    size_t buf_f = (size_t)nE * 96;
    int* ib     = (int*)(buf + buf_f);
    int* cntA   = ib;                // nN
    int* cursor = ib + nN;           // nN
    int* rowptr = ib + 2 * nN;       // nN+1
    int* eidsp  = ib + 3 * nN + 1;   // nE
    size_t need = (8192 + buf_f) * 4 + ((size_t)3 * nN + 1 + nE) * 4;

    prep_kernel<<<24, 256, 0, stream>>>(Wt, wtT);

    if (ws_size >= need) {
        hipMemsetAsync(cntA, 0, (size_t)2 * nN * sizeof(int), stream);
        hist_kernel<<<(nE + 255) / 256, 256, 0, stream>>>(ei, cntA, nE);
        scan_kernel<<<1, 1024, 0, stream>>>(cntA, rowptr, nN);
        bump_kernel<<<(nE + 255) / 256, 256, 0, stream>>>(ei, rowptr, cursor, eidsp, nE);
        edge_mlp_store_kernel<<<(nE + 255) / 256, 256, 0, stream>>>(
            ea, ew, W1, b1, W2, b2, W3, b3, buf, nE);
        node_kernel<<<(nN + 7) / 8, 256, 0, stream>>>(
            X, wtT, nullptr, rowptr, eidsp, buf, (float*)d_out, nN, 1);
    } else {
        float* accp = ws + 8192;     // nN*96 floats
        hipMemsetAsync(accp, 0, (size_t)nN * 96 * sizeof(float), stream);
        edge_mlp_atomic_kernel<<<(nE + 255) / 256, 256, 0, stream>>>(
            ea, ew, ei, W1, b1, W2, b2, W3, b3, accp, nE);
        node_kernel<<<(nN + 7) / 8, 256, 0, stream>>>(
            X, wtT, accp, nullptr, nullptr, nullptr, (float*)d_out, nN, 0);
    }
}

// Round 4
// 545.041 us; speedup vs baseline: 4.1851x; 2.1506x over previous
//
#include <hip/hip_runtime.h>
#include <math.h>

// N=50000, E=400000, U=32, R=32. All fp32; edge_index int32.
//
// R3 post-mortem: edge MLP was scalar-pipe-bound — wave-uniform weight loads
// (36.75KB > sL1) re-fetched per wave through the single per-CU scalar unit
// (VALUBusy 13.6%, 843us). R4: weights staged in LDS, read as wave-uniform
// ds_read_b128 broadcasts (conflict-free, per-CU LDS pipe, overlaps VALU).
// Also: parallel 3-phase scan (was 49 serialized block-iterations), and CSR
// slot-ordered buf stores so the node gather is a contiguous stream (no eids
// indirection / dependent loads).

__device__ __forceinline__ float fast_silu(float x){
    return x * __builtin_amdgcn_rcpf(1.0f + __expf(-x));
}

// ---------------- prep: transpose Wt [6][32m][32k] -> wtT [6][32k][32m] -------
__global__ __launch_bounds__(256) void prep_kernel(
    const float* __restrict__ Wt, float* __restrict__ wtT)
{
    int i = blockIdx.x * 256 + threadIdx.x;
    if (i < 6144) {
        int l = i >> 10, rem = i & 1023, k = rem >> 5, m = rem & 31;
        wtT[i] = Wt[(l << 10) + (m << 5) + k];
    }
}

// ---------------- CSR build ---------------------------------------------------
__global__ __launch_bounds__(256) void hist_kernel(
    const int* __restrict__ edge_index, int* __restrict__ cnt, int nE)
{
    int e = blockIdx.x * 256 + threadIdx.x;
    if (e < nE) atomicAdd(&cnt[edge_index[nE + e]], 1);
}

// phase A: per-1024-chunk exclusive scan, chunk totals to csum
__global__ __launch_bounds__(1024) void scanA_kernel(
    const int* __restrict__ cnt, int* __restrict__ rowptr,
    int* __restrict__ csum, int nN)
{
    __shared__ int wsum[16];
    __shared__ int wpre[16];
    int tid = threadIdx.x, lane = tid & 63, wid = tid >> 6;
    int i = blockIdx.x * 1024 + tid;
    int orig = (i < nN) ? cnt[i] : 0;
    int v = orig;
    #pragma unroll
    for (int d = 1; d < 64; d <<= 1) { int o = __shfl_up(v, d); if (lane >= d) v += o; }
    if (lane == 63) wsum[wid] = v;
    __syncthreads();
    if (wid == 0) {
        int s = (lane < 16) ? wsum[lane] : 0;
        #pragma unroll
        for (int d = 1; d < 16; d <<= 1) { int o = __shfl_up(s, d); if (lane >= d) s += o; }
        if (lane < 16) wpre[lane] = s;
    }
    __syncthreads();
    int badd = wid ? wpre[wid - 1] : 0;
    if (i < nN) rowptr[i] = badd + v - orig;   // exclusive within chunk
    if (tid == 1023) csum[blockIdx.x] = badd + v;
}

// phase B: single wave scans the (<=64) chunk totals -> exclusive offsets
__global__ __launch_bounds__(64) void scanB_kernel(
    int* __restrict__ csum, int* __restrict__ rowptr, int nChunks, int nN)
{
    int lane = threadIdx.x;
    int orig = (lane < nChunks) ? csum[lane] : 0;
    int s = orig;
    #pragma unroll
    for (int d = 1; d < 64; d <<= 1) { int o = __shfl_up(s, d); if (lane >= d) s += o; }
    if (lane < nChunks) csum[lane] = s - orig;   // exclusive
    if (lane == 63) rowptr[nN] = s;              // grand total (nE)
}

// phase C: add chunk offsets
__global__ __launch_bounds__(1024) void scanC_kernel(
    const int* __restrict__ csum, int* __restrict__ rowptr, int nN)
{
    int i = blockIdx.x * 1024 + threadIdx.x;
    if (i < nN) rowptr[i] += csum[i >> 10];
}

// per-edge CSR slot
__global__ __launch_bounds__(256) void bump_kernel(
    const int* __restrict__ edge_index, const int* __restrict__ rowptr,
    int* __restrict__ cursor, int* __restrict__ eslot, int nE)
{
    int e = blockIdx.x * 256 + threadIdx.x;
    if (e >= nE) return;
    int dst = edge_index[nE + e];
    eslot[e] = rowptr[dst] + atomicAdd(&cursor[dst], 1);
}

// ---------------- edge: LDS-staged weights, MLP, store at CSR slot ------------
__global__ __launch_bounds__(256) void edge_mlp_store_kernel(
    const float* __restrict__ edge_attr,
    const float* __restrict__ edge_weight,
    const int* __restrict__ eslot,
    const float* __restrict__ w1, const float* __restrict__ b1,
    const float* __restrict__ w2, const float* __restrict__ b2,
    const float* __restrict__ w3, const float* __restrict__ b3,
    float* __restrict__ buf, int nE)
{
    __shared__ __align__(16) float sw1[1024];
    __shared__ __align__(16) float sw2[2048];
    __shared__ __align__(16) float sw3[6144];
    __shared__ float sb1[32], sb2[64], sb3[96];

    int tid = threadIdx.x;
    for (int i = tid; i < 1024; i += 256) sw1[i] = w1[i];
    for (int i = tid; i < 2048; i += 256) sw2[i] = w2[i];
    for (int i = tid; i < 6144; i += 256) sw3[i] = w3[i];
    if (tid < 32) sb1[tid] = b1[tid];
    if (tid < 64) sb2[tid] = b2[tid];
    if (tid < 96) sb3[tid] = b3[tid];
    __syncthreads();

    int e = blockIdx.x * 256 + tid;
    if (e >= nE) return;

    const float4* rq = reinterpret_cast<const float4*>(edge_attr) + (size_t)e * 8;
    float ea[32];
    #pragma unroll
    for (int i = 0; i < 8; ++i) {
        float4 q = rq[i];
        ea[4*i] = q.x; ea[4*i+1] = q.y; ea[4*i+2] = q.z; ea[4*i+3] = q.w;
    }

    // layer 1: 32->32. Weight reads are wave-uniform ds_read_b128 broadcasts.
    float h1[32];
    for (int m = 0; m < 32; ++m) {
        const float4* wq = reinterpret_cast<const float4*>(sw1 + m*32);
        float a = sb1[m];
        #pragma unroll
        for (int k = 0; k < 8; ++k) {
            float4 w = wq[k];
            a += ea[4*k]*w.x + ea[4*k+1]*w.y + ea[4*k+2]*w.z + ea[4*k+3]*w.w;
        }
        h1[m] = fast_silu(a);
    }
    // layer 2: 32->64
    float h2[64];
    for (int m = 0; m < 64; ++m) {
        const float4* wq = reinterpret_cast<const float4*>(sw2 + m*32);
        float a = sb2[m];
        #pragma unroll
        for (int k = 0; k < 8; ++k) {
            float4 w = wq[k];
            a += h1[4*k]*w.x + h1[4*k+1]*w.y + h1[4*k+2]*w.z + h1[4*k+3]*w.w;
        }
        h2[m] = fast_silu(a);
    }
    float ew = edge_weight[e];
    float Cc = (ew < 5.0f) ? 0.5f * (__cosf(ew * (3.14159265358979323846f/5.0f)) + 1.0f) : 0.0f;

    float4* op = reinterpret_cast<float4*>(buf + (size_t)eslot[e] * 96);
    // layer 3: 64->96, store CSR-slot-ordered
    for (int m4 = 0; m4 < 24; ++m4) {
        float o[4];
        #pragma unroll
        for (int j = 0; j < 4; ++j) {
            int m = m4 * 4 + j;
            const float4* wq = reinterpret_cast<const float4*>(sw3 + m*64);
            float a = sb3[m];
            #pragma unroll
            for (int k = 0; k < 16; ++k) {
                float4 w = wq[k];
                a += h2[4*k]*w.x + h2[4*k+1]*w.y + h2[4*k+2]*w.z + h2[4*k+3]*w.w;
            }
            o[j] = fast_silu(a) * Cc;
        }
        op[m4] = make_float4(o[0], o[1], o[2], o[3]);
    }
}

// ---------------- node kernel -------------------------------------------------
__device__ __forceinline__ void comp_linear(
    const float* __restrict__ w012, const float* __restrict__ cb,
    int u, float& Il, float* a, float* s)
{
    Il = 0.f; a[0]=a[1]=a[2]=0.f;
    s[0]=s[1]=s[2]=s[3]=s[4]=s[5]=0.f;
    #pragma unroll
    for (int k = 0; k < 32; ++k) {
        float w0 = w012[          k*32 + u];
        float w1 = w012[1024 + k*32 + u];
        float w2 = w012[2048 + k*32 + u];
        Il   += cb[       k] * w0;
        a[0] += cb[ 32 + k] * w1;
        a[1] += cb[ 64 + k] * w1;
        a[2] += cb[ 96 + k] * w1;
        s[0] += cb[128 + k] * w2;
        s[1] += cb[160 + k] * w2;
        s[2] += cb[192 + k] * w2;
        s[3] += cb[224 + k] * w2;
        s[4] += cb[256 + k] * w2;
        s[5] += cb[288 + k] * w2;
    }
}

__device__ __forceinline__ void compose(float Il, const float* a, const float* s, float (&T)[3][3])
{
    T[0][0] =  Il  + s[0]; T[0][1] =  a[0] + s[1]; T[0][2] =  a[1] + s[2];
    T[1][0] = -a[0] + s[1]; T[1][1] =  Il  + s[3]; T[1][2] =  a[2] + s[4];
    T[2][0] = -a[1] + s[2]; T[2][1] = -a[2] + s[4]; T[2][2] =  Il  + s[5];
}

__global__ __launch_bounds__(256) void node_kernel(
    const float* __restrict__ X,
    const float* __restrict__ wtT,      // [6][32k][32m]
    const int* __restrict__ rowptr,
    const float* __restrict__ buf,      // [nE][96], CSR slot order
    float* __restrict__ out, int nN)
{
    __shared__ float sWt[6 * 1024];
    __shared__ float sC[8][10][32];

    int tid = threadIdx.x;
    for (int i = tid; i < 6144; i += 256) sWt[i] = wtT[i];

    int ln = tid >> 5, u = tid & 31;
    int n  = blockIdx.x * 8 + ln;
    if (n >= nN) n = nN - 1;
    float* cb = &sC[ln][0][0];

    // contiguous stream of this node's edge outputs (slot-ordered)
    int r0 = rowptr[n], r1 = rowptr[n + 1];
    float sIv = 0.f, sAv = 0.f, sSv = 0.f;
    const float* bp = buf + (size_t)r0 * 96 + 3 * u;
    for (int i = r0; i < r1; ++i, bp += 96) {
        sIv += bp[0]; sAv += bp[1]; sSv += bp[2];
    }

    const float* xp = X + (size_t)n * 288 + u;
    float x[3][3];
    float nrm = 1.0f;
    #pragma unroll
    for (int i = 0; i < 3; ++i)
        #pragma unroll
        for (int j = 0; j < 3; ++j) {
            float v = xp[(i*3 + j) * 32];
            x[i][j] = v; nrm += v * v;
        }
    float inv = 1.0f / nrm;
    #pragma unroll
    for (int i = 0; i < 3; ++i)
        #pragma unroll
        for (int j = 0; j < 3; ++j) x[i][j] *= inv;   // Xn

    float tI = (x[0][0] + x[1][1] + x[2][2]) * (1.0f/3.0f);
    cb[0*32 + u] = tI;
    cb[1*32 + u] = 0.5f * (x[0][1] - x[1][0]);
    cb[2*32 + u] = 0.5f * (x[0][2] - x[2][0]);
    cb[3*32 + u] = 0.5f * (x[1][2] - x[2][1]);
    cb[4*32 + u] = x[0][0] - tI;
    cb[5*32 + u] = 0.5f * (x[0][1] + x[1][0]);
    cb[6*32 + u] = 0.5f * (x[0][2] + x[2][0]);
    cb[7*32 + u] = x[1][1] - tI;
    cb[8*32 + u] = 0.5f * (x[1][2] + x[2][1]);
    cb[9*32 + u] = x[2][2] - tI;
    __syncthreads();

    float Il, a[3], s[6];
    comp_linear(sWt, cb, u, Il, a, s);

    float Ym[3][3], Gm[3][3];
    compose(Il, a, s, Ym);
    float am[3] = {a[0]*sAv, a[1]*sAv, a[2]*sAv};
    float sm[6] = {s[0]*sSv, s[1]*sSv, s[2]*sSv, s[3]*sSv, s[4]*sSv, s[5]*sSv};
    compose(Il * sIv, am, sm, Gm);

    float M[3][3]; float np1 = 1.0f;
    #pragma unroll
    for (int i = 0; i < 3; ++i)
        #pragma unroll
        for (int l = 0; l < 3; ++l) {
            float v = 0.f;
            #pragma unroll
            for (int j = 0; j < 3; ++j) v += Ym[i][j]*Gm[j][l] + Gm[i][j]*Ym[j][l];
            M[i][l] = v; np1 += v * v;
        }
    float rinv = 1.0f / np1;
    float tI2 = (M[0][0] + M[1][1] + M[2][2]) * (1.0f/3.0f);

    __syncthreads();
    cb[0*32 + u] = tI2 * rinv;
    cb[1*32 + u] = 0.5f * (M[0][1] - M[1][0]) * rinv;
    cb[2*32 + u] = 0.5f * (M[0][2] - M[2][0]) * rinv;
    cb[3*32 + u] = 0.5f * (M[1][2] - M[2][1]) * rinv;
    cb[4*32 + u] = (M[0][0] - tI2) * rinv;
    cb[5*32 + u] = 0.5f * (M[0][1] + M[1][0]) * rinv;
    cb[6*32 + u] = 0.5f * (M[0][2] + M[2][0]) * rinv;
    cb[7*32 + u] = (M[1][1] - tI2) * rinv;
    cb[8*32 + u] = 0.5f * (M[1][2] + M[2][1]) * rinv;
    cb[9*32 + u] = (M[2][2] - tI2) * rinv;
    __syncthreads();

    comp_linear(sWt + 3*1024, cb, u, Il, a, s);
    float D[3][3];
    compose(Il, a, s, D);

    float* op = out + (size_t)n * 288 + u;
    #pragma unroll
    for (int i = 0; i < 3; ++i)
        #pragma unroll
        for (int l = 0; l < 3; ++l) {
            float v = x[i][l] + D[i][l];
            #pragma unroll
            for (int j = 0; j < 3; ++j) v += D[i][j] * D[j][l];
            op[(i*3 + l) * 32] = v;
        }
}

extern "C" void kernel_launch(void* const* d_in, const int* in_sizes, int n_in,
                              void* d_out, int out_size, void* d_ws, size_t ws_size,
                              hipStream_t stream) {
    const float* X   = (const float*)d_in[0];
    const int*   ei  = (const int*)d_in[1];
    const float* ew  = (const float*)d_in[2];
    const float* ea  = (const float*)d_in[3];
    const float* W1  = (const float*)d_in[4];
    const float* b1  = (const float*)d_in[5];
    const float* W2  = (const float*)d_in[6];
    const float* b2  = (const float*)d_in[7];
    const float* W3  = (const float*)d_in[8];
    const float* b3  = (const float*)d_in[9];
    const float* Wt  = (const float*)d_in[10];

    int nE = in_sizes[2];          // 400000
    int nN = in_sizes[0] / 288;    // 50000
    int nChunks = (nN + 1023) / 1024;

    float* ws  = (float*)d_ws;
    float* wtT = ws;                           // 6144 floats (pad to 8192)
    float* buf = ws + 8192;                    // nE*96 floats
    size_t buf_f = (size_t)nE * 96;
    int* ib     = (int*)(buf + buf_f);
    int* cntA   = ib;                // nN   (becomes scratch)
    int* cursor = ib + nN;           // nN
    int* rowptr = ib + 2 * nN;       // nN+1
    int* eslot  = ib + 3 * nN + 1;   // nE
    int* csum   = ib + 3 * nN + 1 + nE;  // nChunks (<=64)

    prep_kernel<<<24, 256, 0, stream>>>(Wt, wtT);
    hipMemsetAsync(cntA, 0, (size_t)2 * nN * sizeof(int), stream);
    hist_kernel<<<(nE + 255) / 256, 256, 0, stream>>>(ei, cntA, nE);
    scanA_kernel<<<nChunks, 1024, 0, stream>>>(cntA, rowptr, csum, nN);
    scanB_kernel<<<1, 64, 0, stream>>>(csum, rowptr, nChunks, nN);
    scanC_kernel<<<nChunks, 1024, 0, stream>>>(csum, rowptr, nN);
    bump_kernel<<<(nE + 255) / 256, 256, 0, stream>>>(ei, rowptr, cursor, eslot, nE);
    edge_mlp_store_kernel<<<(nE + 255) / 256, 256, 0, stream>>>(
        ea, ew, eslot, W1, b1, W2, b2, W3, b3, buf, nE);
    node_kernel<<<(nN + 7) / 8, 256, 0, stream>>>(
        X, wtT, rowptr, buf, (float*)d_out, nN);
}

// Round 6
// 356.317 us; speedup vs baseline: 6.4018x; 1.5297x over previous
//
#include <hip/hip_runtime.h>
#include <math.h>

// N=50000, E=400000, U=32, R=32. All fp32; edge_index int32.
//
// R4 post-mortem: edge MLP occupancy-capped (18.5%) by 37.9KB LDS weight stage;
// dependent ds_read_b128->fmac chains stall on LDS latency (VALUBusy 54%).
// R5/R6: weights+activations f16 (fp32 accumulate via v_dot2_f32_f16):
//  - LDS 37.9 -> 18.75KB (2x blocks/CU), broadcasts 2304 -> 1152/wave,
//  - FMA instrs halve (dot2), activations packed with v_cvt_pkrtz,
//  - bump kernel merged into edge kernel (slot computed inline).
// R6 fix: bit-cast pkrtz result (__fp16 vec) to h2 (_Float16 vec).

typedef _Float16 h2 __attribute__((ext_vector_type(2)));
typedef __fp16   p2 __attribute__((ext_vector_type(2)));

__device__ __forceinline__ h2 as_h2(unsigned u){ union{unsigned x; h2 h;} c; c.x=u; return c.h; }

__device__ __forceinline__ float dot2(h2 a, h2 b, float c){
#if __has_builtin(__builtin_amdgcn_fdot2)
    return __builtin_amdgcn_fdot2(a, b, c, false);
#else
    return c + (float)a.x*(float)b.x + (float)a.y*(float)b.y;
#endif
}

__device__ __forceinline__ h2 pk(float a, float b){
#if __has_builtin(__builtin_amdgcn_cvt_pkrtz)
    union { p2 p; h2 h; } c;
    c.p = __builtin_amdgcn_cvt_pkrtz(a, b);
    return c.h;
#else
    h2 r; r.x=(_Float16)a; r.y=(_Float16)b; return r;
#endif
}

__device__ __forceinline__ float fast_silu(float x){
    return x * __builtin_amdgcn_rcpf(1.0f + __expf(-x));
}

// ---- prep: transpose Wt, gather biases, convert W1/W2/W3 to f16 --------------
__global__ __launch_bounds__(256) void prep_kernel(
    const float* __restrict__ Wt,
    const float* __restrict__ W1, const float* __restrict__ b1,
    const float* __restrict__ W2, const float* __restrict__ b2,
    const float* __restrict__ W3, const float* __restrict__ b3,
    float* __restrict__ wtT, float* __restrict__ ball, unsigned* __restrict__ whall)
{
    int i = blockIdx.x * 256 + threadIdx.x;
    if (i < 6144) {
        int l = i >> 10, rem = i & 1023, k = rem >> 5, m = rem & 31;
        wtT[i] = Wt[(l << 10) + (m << 5) + k];
    }
    if (i < 192) ball[i] = (i < 32) ? b1[i] : (i < 96) ? b2[i-32] : b3[i-96];
    if (i < 9216) {
        float v = (i < 1024) ? W1[i] : (i < 3072) ? W2[i-1024] : W3[i-3072];
        reinterpret_cast<_Float16*>(whall)[i] = (_Float16)v;
    }
}

// ---- CSR build ---------------------------------------------------------------
__global__ __launch_bounds__(256) void hist_kernel(
    const int* __restrict__ edge_index, int* __restrict__ cnt, int nE)
{
    int e = blockIdx.x * 256 + threadIdx.x;
    if (e < nE) atomicAdd(&cnt[edge_index[nE + e]], 1);
}

__global__ __launch_bounds__(1024) void scanA_kernel(
    const int* __restrict__ cnt, int* __restrict__ rowptr,
    int* __restrict__ csum, int nN)
{
    __shared__ int wsum[16];
    __shared__ int wpre[16];
    int tid = threadIdx.x, lane = tid & 63, wid = tid >> 6;
    int i = blockIdx.x * 1024 + tid;
    int orig = (i < nN) ? cnt[i] : 0;
    int v = orig;
    #pragma unroll
    for (int d = 1; d < 64; d <<= 1) { int o = __shfl_up(v, d); if (lane >= d) v += o; }
    if (lane == 63) wsum[wid] = v;
    __syncthreads();
    if (wid == 0) {
        int s = (lane < 16) ? wsum[lane] : 0;
        #pragma unroll
        for (int d = 1; d < 16; d <<= 1) { int o = __shfl_up(s, d); if (lane >= d) s += o; }
        if (lane < 16) wpre[lane] = s;
    }
    __syncthreads();
    int badd = wid ? wpre[wid - 1] : 0;
    if (i < nN) rowptr[i] = badd + v - orig;
    if (tid == 1023) csum[blockIdx.x] = badd + v;
}

__global__ __launch_bounds__(64) void scanB_kernel(
    int* __restrict__ csum, int* __restrict__ rowptr, int nChunks, int nN)
{
    int lane = threadIdx.x;
    int orig = (lane < nChunks) ? csum[lane] : 0;
    int s = orig;
    #pragma unroll
    for (int d = 1; d < 64; d <<= 1) { int o = __shfl_up(s, d); if (lane >= d) s += o; }
    if (lane < nChunks) csum[lane] = s - orig;
    if (lane == 63) rowptr[nN] = s;
}

__global__ __launch_bounds__(1024) void scanC_kernel(
    const int* __restrict__ csum, int* __restrict__ rowptr, int nN)
{
    int i = blockIdx.x * 1024 + threadIdx.x;
    if (i < nN) rowptr[i] += csum[i >> 10];
}

// ---- edge: f16 MLP (fp32 accum), slot computed inline, store 96 floats -------
__global__ __launch_bounds__(256) void edge_mlp_store_kernel(
    const float* __restrict__ edge_attr,
    const float* __restrict__ edge_weight,
    const int* __restrict__ edge_index,
    const int* __restrict__ rowptr,
    int* __restrict__ cursor,
    const unsigned* __restrict__ whall,   // f16 weights: w1[512u] w2[1024u] w3[3072u]
    const float* __restrict__ ball,       // 192 fp32 biases
    float* __restrict__ buf, int nE)
{
    __shared__ __align__(16) unsigned swu[4608];
    __shared__ float sb[192];
    int tid = threadIdx.x;
    for (int i = tid; i < 4608; i += 256) swu[i] = whall[i];
    if (tid < 192) sb[tid] = ball[tid];
    __syncthreads();

    int e = blockIdx.x * 256 + tid;
    if (e >= nE) return;

    // load + pack edge_attr row (32 f32 -> 16 h2)
    const float4* rq = reinterpret_cast<const float4*>(edge_attr) + (size_t)e * 8;
    h2 eah[16];
    #pragma unroll
    for (int i = 0; i < 8; ++i) {
        float4 q = rq[i];
        eah[2*i]   = pk(q.x, q.y);
        eah[2*i+1] = pk(q.z, q.w);
    }
    int dst  = edge_index[nE + e];
    int slot = rowptr[dst] + atomicAdd(&cursor[dst], 1);   // start atomic early
    float ew = edge_weight[e];
    float Cc = (ew < 5.0f) ? 0.5f * (__cosf(ew * 0.6283185307179586f) + 1.0f) : 0.0f;

    // layer 1: 32->32, m-pairs (rows are 4 uint4 each)
    h2 h1h[16];
    const uint4* base1 = reinterpret_cast<const uint4*>(swu);
    #pragma unroll
    for (int mp = 0; mp < 16; ++mp) {
        float a0 = sb[2*mp], a1 = sb[2*mp+1];
        const uint4* w0 = base1 + 2*mp*4;
        #pragma unroll
        for (int q = 0; q < 4; ++q) {
            uint4 x = w0[q], y = w0[q+4];
            a0 = dot2(eah[4*q+0], as_h2(x.x), a0);
            a0 = dot2(eah[4*q+1], as_h2(x.y), a0);
            a0 = dot2(eah[4*q+2], as_h2(x.z), a0);
            a0 = dot2(eah[4*q+3], as_h2(x.w), a0);
            a1 = dot2(eah[4*q+0], as_h2(y.x), a1);
            a1 = dot2(eah[4*q+1], as_h2(y.y), a1);
            a1 = dot2(eah[4*q+2], as_h2(y.z), a1);
            a1 = dot2(eah[4*q+3], as_h2(y.w), a1);
        }
        h1h[mp] = pk(fast_silu(a0), fast_silu(a1));
    }

    // layer 2: 32->64
    h2 h2h[32];
    const uint4* base2 = reinterpret_cast<const uint4*>(swu + 512);
    #pragma unroll
    for (int mp = 0; mp < 32; ++mp) {
        float a0 = sb[32 + 2*mp], a1 = sb[32 + 2*mp+1];
        const uint4* w0 = base2 + 2*mp*4;
        #pragma unroll
        for (int q = 0; q < 4; ++q) {
            uint4 x = w0[q], y = w0[q+4];
            a0 = dot2(h1h[4*q+0], as_h2(x.x), a0);
            a0 = dot2(h1h[4*q+1], as_h2(x.y), a0);
            a0 = dot2(h1h[4*q+2], as_h2(x.z), a0);
            a0 = dot2(h1h[4*q+3], as_h2(x.w), a0);
            a1 = dot2(h1h[4*q+0], as_h2(y.x), a1);
            a1 = dot2(h1h[4*q+1], as_h2(y.y), a1);
            a1 = dot2(h1h[4*q+2], as_h2(y.z), a1);
            a1 = dot2(h1h[4*q+3], as_h2(y.w), a1);
        }
        h2h[mp] = pk(fast_silu(a0), fast_silu(a1));
    }

    // layer 3: 64->96, groups of 4 outputs (rows are 8 uint4 each)
    float4* op = reinterpret_cast<float4*>(buf + (size_t)slot * 96);
    const uint4* base3 = reinterpret_cast<const uint4*>(swu + 1536);
    for (int g = 0; g < 24; ++g) {
        float a0 = sb[96+4*g], a1 = sb[96+4*g+1], a2 = sb[96+4*g+2], a3 = sb[96+4*g+3];
        const uint4* w0 = base3 + 4*g*8;
        #pragma unroll
        for (int q = 0; q < 8; ++q) {
            uint4 x = w0[q], y = w0[q+8], z = w0[q+16], w = w0[q+24];
            a0 = dot2(h2h[4*q+0], as_h2(x.x), a0);
            a0 = dot2(h2h[4*q+1], as_h2(x.y), a0);
            a0 = dot2(h2h[4*q+2], as_h2(x.z), a0);
            a0 = dot2(h2h[4*q+3], as_h2(x.w), a0);
            a1 = dot2(h2h[4*q+0], as_h2(y.x), a1);
            a1 = dot2(h2h[4*q+1], as_h2(y.y), a1);
            a1 = dot2(h2h[4*q+2], as_h2(y.z), a1);
            a1 = dot2(h2h[4*q+3], as_h2(y.w), a1);
            a2 = dot2(h2h[4*q+0], as_h2(z.x), a2);
            a2 = dot2(h2h[4*q+1], as_h2(z.y), a2);
            a2 = dot2(h2h[4*q+2], as_h2(z.z), a2);
            a2 = dot2(h2h[4*q+3], as_h2(z.w), a2);
            a3 = dot2(h2h[4*q+0], as_h2(w.x), a3);
            a3 = dot2(h2h[4*q+1], as_h2(w.y), a3);
            a3 = dot2(h2h[4*q+2], as_h2(w.z), a3);
            a3 = dot2(h2h[4*q+3], as_h2(w.w), a3);
        }
        op[g] = make_float4(fast_silu(a0)*Cc, fast_silu(a1)*Cc,
                            fast_silu(a2)*Cc, fast_silu(a3)*Cc);
    }
}

// ---- node kernel (unchanged from R4) -----------------------------------------
__device__ __forceinline__ void comp_linear(
    const float* __restrict__ w012, const float* __restrict__ cb,
    int u, float& Il, float* a, float* s)
{
    Il = 0.f; a[0]=a[1]=a[2]=0.f;
    s[0]=s[1]=s[2]=s[3]=s[4]=s[5]=0.f;
    #pragma unroll
    for (int k = 0; k < 32; ++k) {
        float w0 = w012[          k*32 + u];
        float w1 = w012[1024 + k*32 + u];
        float w2 = w012[2048 + k*32 + u];
        Il   += cb[       k] * w0;
        a[0] += cb[ 32 + k] * w1;
        a[1] += cb[ 64 + k] * w1;
        a[2] += cb[ 96 + k] * w1;
        s[0] += cb[128 + k] * w2;
        s[1] += cb[160 + k] * w2;
        s[2] += cb[192 + k] * w2;
        s[3] += cb[224 + k] * w2;
        s[4] += cb[256 + k] * w2;
        s[5] += cb[288 + k] * w2;
    }
}

__device__ __forceinline__ void compose(float Il, const float* a, const float* s, float (&T)[3][3])
{
    T[0][0] =  Il  + s[0]; T[0][1] =  a[0] + s[1]; T[0][2] =  a[1] + s[2];
    T[1][0] = -a[0] + s[1]; T[1][1] =  Il  + s[3]; T[1][2] =  a[2] + s[4];
    T[2][0] = -a[1] + s[2]; T[2][1] = -a[2] + s[4]; T[2][2] =  Il  + s[5];
}

__global__ __launch_bounds__(256) void node_kernel(
    const float* __restrict__ X,
    const float* __restrict__ wtT,
    const int* __restrict__ rowptr,
    const float* __restrict__ buf,
    float* __restrict__ out, int nN)
{
    __shared__ float sWt[6 * 1024];
    __shared__ float sC[8][10][32];

    int tid = threadIdx.x;
    for (int i = tid; i < 6144; i += 256) sWt[i] = wtT[i];

    int ln = tid >> 5, u = tid & 31;
    int n  = blockIdx.x * 8 + ln;
    if (n >= nN) n = nN - 1;
    float* cb = &sC[ln][0][0];

    int r0 = rowptr[n], r1 = rowptr[n + 1];
    float sIv = 0.f, sAv = 0.f, sSv = 0.f;
    const float* bp = buf + (size_t)r0 * 96 + 3 * u;
    for (int i = r0; i < r1; ++i, bp += 96) {
        sIv += bp[0]; sAv += bp[1]; sSv += bp[2];
    }

    const float* xp = X + (size_t)n * 288 + u;
    float x[3][3];
    float nrm = 1.0f;
    #pragma unroll
    for (int i = 0; i < 3; ++i)
        #pragma unroll
        for (int j = 0; j < 3; ++j) {
            float v = xp[(i*3 + j) * 32];
            x[i][j] = v; nrm += v * v;
        }
    float inv = 1.0f / nrm;
    #pragma unroll
    for (int i = 0; i < 3; ++i)
        #pragma unroll
        for (int j = 0; j < 3; ++j) x[i][j] *= inv;

    float tI = (x[0][0] + x[1][1] + x[2][2]) * (1.0f/3.0f);
    cb[0*32 + u] = tI;
    cb[1*32 + u] = 0.5f * (x[0][1] - x[1][0]);
    cb[2*32 + u] = 0.5f * (x[0][2] - x[2][0]);
    cb[3*32 + u] = 0.5f * (x[1][2] - x[2][1]);
    cb[4*32 + u] = x[0][0] - tI;
    cb[5*32 + u] = 0.5f * (x[0][1] + x[1][0]);
    cb[6*32 + u] = 0.5f * (x[0][2] + x[2][0]);
    cb[7*32 + u] = x[1][1] - tI;
    cb[8*32 + u] = 0.5f * (x[1][2] + x[2][1]);
    cb[9*32 + u] = x[2][2] - tI;
    __syncthreads();

    float Il, a[3], s[6];
    comp_linear(sWt, cb, u, Il, a, s);

    float Ym[3][3], Gm[3][3];
    compose(Il, a, s, Ym);
    float am[3] = {a[0]*sAv, a[1]*sAv, a[2]*sAv};
    float sm[6] = {s[0]*sSv, s[1]*sSv, s[2]*sSv, s[3]*sSv, s[4]*sSv, s[5]*sSv};
    compose(Il * sIv, am, sm, Gm);

    float M[3][3]; float np1 = 1.0f;
    #pragma unroll
    for (int i = 0; i < 3; ++i)
        #pragma unroll
        for (int l = 0; l < 3; ++l) {
            float v = 0.f;
            #pragma unroll
            for (int j = 0; j < 3; ++j) v += Ym[i][j]*Gm[j][l] + Gm[i][j]*Ym[j][l];
            M[i][l] = v; np1 += v * v;
        }
    float rinv = 1.0f / np1;
    float tI2 = (M[0][0] + M[1][1] + M[2][2]) * (1.0f/3.0f);

    __syncthreads();
    cb[0*32 + u] = tI2 * rinv;
    cb[1*32 + u] = 0.5f * (M[0][1] - M[1][0]) * rinv;
    cb[2*32 + u] = 0.5f * (M[0][2] - M[2][0]) * rinv;
    cb[3*32 + u] = 0.5f * (M[1][2] - M[2][1]) * rinv;
    cb[4*32 + u] = (M[0][0] - tI2) * rinv;
    cb[5*32 + u] = 0.5f * (M[0][1] + M[1][0]) * rinv;
    cb[6*32 + u] = 0.5f * (M[0][2] + M[2][0]) * rinv;
    cb[7*32 + u] = (M[1][1] - tI2) * rinv;
    cb[8*32 + u] = 0.5f * (M[1][2] + M[2][1]) * rinv;
    cb[9*32 + u] = (M[2][2] - tI2) * rinv;
    __syncthreads();

    comp_linear(sWt + 3*1024, cb, u, Il, a, s);
    float D[3][3];
    compose(Il, a, s, D);

    float* op = out + (size_t)n * 288 + u;
    #pragma unroll
    for (int i = 0; i < 3; ++i)
        #pragma unroll
        for (int l = 0; l < 3; ++l) {
            float v = x[i][l] + D[i][l];
            #pragma unroll
            for (int j = 0; j < 3; ++j) v += D[i][j] * D[j][l];
            op[(i*3 + l) * 32] = v;
        }
}

extern "C" void kernel_launch(void* const* d_in, const int* in_sizes, int n_in,
                              void* d_out, int out_size, void* d_ws, size_t ws_size,
                              hipStream_t stream) {
    const float* X   = (const float*)d_in[0];
    const int*   ei  = (const int*)d_in[1];
    const float* ew  = (const float*)d_in[2];
    const float* ea  = (const float*)d_in[3];
    const float* W1  = (const float*)d_in[4];
    const float* b1  = (const float*)d_in[5];
    const float* W2  = (const float*)d_in[6];
    const float* b2  = (const float*)d_in[7];
    const float* W3  = (const float*)d_in[8];
    const float* b3  = (const float*)d_in[9];
    const float* Wt  = (const float*)d_in[10];

    int nE = in_sizes[2];          // 400000
    int nN = in_sizes[0] / 288;    // 50000
    int nChunks = (nN + 1023) / 1024;

    float* ws       = (float*)d_ws;
    float* wtT      = ws;                        // 6144 floats (pad to 8192)
    float* ball     = ws + 8192;                 // 192 floats (pad to 256)
    unsigned* whall = (unsigned*)(ws + 8448);    // 4608 uints (9216 f16)
    float* buf      = ws + 8448 + 4608;          // nE*96 floats (16B-aligned)
    size_t buf_f    = (size_t)nE * 96;
    int* ib     = (int*)(buf + buf_f);
    int* cntA   = ib;                 // nN
    int* cursor = ib + nN;            // nN
    int* rowptr = ib + 2 * nN;        // nN+1
    int* csum   = ib + 3 * nN + 1;    // nChunks (<=64)

    prep_kernel<<<36, 256, 0, stream>>>(Wt, W1, b1, W2, b2, W3, b3, wtT, ball, whall);
    (void)hipMemsetAsync(cntA, 0, (size_t)2 * nN * sizeof(int), stream);
    hist_kernel<<<(nE + 255) / 256, 256, 0, stream>>>(ei, cntA, nE);
    scanA_kernel<<<nChunks, 1024, 0, stream>>>(cntA, rowptr, csum, nN);
    scanB_kernel<<<1, 64, 0, stream>>>(csum, rowptr, nChunks, nN);
    scanC_kernel<<<nChunks, 1024, 0, stream>>>(csum, rowptr, nN);
    edge_mlp_store_kernel<<<(nE + 255) / 256, 256, 0, stream>>>(
        ea, ew, ei, rowptr, cursor, whall, ball, buf, nE);
    node_kernel<<<(nN + 7) / 8, 256, 0, stream>>>(
        X, wtT, rowptr, buf, (float*)d_out, nN);
}